// Round 1
// baseline (831.995 us; speedup 1.0000x reference)
//
#include <hip/hip_runtime.h>
#include <math.h>

// HyperbolicGraphConvolution on MI355X.
// N=100000 nodes, D=65 (col 0 is identically 0 through the GCN hops -> use 64),
// E=1.6M edges. Strategy: build CSR buckets once per call (histogram + scan +
// scatter), then 3 gather-style SpMMs with one wave per row (lane d = feature d),
// no atomics in the hot loop. 3-hop accumulator lives in d_out cols 1..64.

__device__ __forceinline__ float waveReduceSum(float v) {
  #pragma unroll
  for (int m = 32; m > 0; m >>= 1) v += __shfl_xor(v, m, 64);
  return v;
}

// t[i,d] = acosh(max(x[i,0], 1+1e-7)) * y_d / max(||y||, 1e-15), y = x[i,1:65]
__global__ __launch_bounds__(256) void k_logmap0(const float* __restrict__ x,
                                                 float* __restrict__ t, int n) {
  int wid = (blockIdx.x * blockDim.x + threadIdx.x) >> 6;
  int lane = threadIdx.x & 63;
  if (wid >= n) return;
  const float* row = x + (size_t)wid * 65;
  float x0 = row[0];
  float y = row[1 + lane];
  float ss = waveReduceSum(y * y);
  float nrm = fmaxf(sqrtf(ss), 1e-15f);
  float theta = fmaxf(x0, 1.0f + 1e-7f);
  t[(size_t)wid * 64 + lane] = acoshf(theta) * (y / nrm);
}

__global__ void k_hist(const int* __restrict__ rows, int* __restrict__ cnt, int e) {
  int i = blockIdx.x * blockDim.x + threadIdx.x;
  int stride = gridDim.x * blockDim.x;
  for (; i < e; i += stride) atomicAdd(&cnt[rows[i]], 1);
}

// Single-block exclusive scan over n counts; writes off[0..n] and rewrites
// cnt[i] = exclusive prefix (serves as the scatter cursor).
__global__ __launch_bounds__(1024) void k_scan(int* __restrict__ cnt,
                                               int* __restrict__ off, int n) {
  __shared__ int part[1024];
  int t = threadIdx.x;
  int ch = (n + 1023) >> 10;
  int b = t * ch;
  int e = min(b + ch, n);
  int s = 0;
  for (int i = b; i < e; ++i) s += cnt[i];
  part[t] = s;
  __syncthreads();
  #pragma unroll
  for (int d = 1; d < 1024; d <<= 1) {
    int v = (t >= d) ? part[t - d] : 0;
    __syncthreads();
    part[t] += v;
    __syncthreads();
  }
  int run = part[t] - s;  // exclusive prefix of this thread's chunk
  for (int i = b; i < e; ++i) {
    int c = cnt[i];
    off[i] = run;
    cnt[i] = run;  // cursor for scatter
    run += c;
  }
  if (t == 1023) off[n] = part[1023];
}

__global__ void k_scatter(const int* __restrict__ rows, const int* __restrict__ cols,
                          const float* __restrict__ vals, int* __restrict__ cursor,
                          int* __restrict__ sc, float* __restrict__ sv, int e) {
  int i = blockIdx.x * blockDim.x + threadIdx.x;
  int stride = gridDim.x * blockDim.x;
  for (; i < e; i += stride) {
    int r = rows[i];
    int p = atomicAdd(&cursor[r], 1);
    sc[p] = cols[i];
    sv[p] = vals[i];
  }
}

// One wave per row: lane d accumulates feature d over the row's edge bucket.
// Edge (col,val) pairs loaded coalesced 64-at-a-time, broadcast via shfl.
// acc points into d_out (stride 65, cols 1..64) and accumulates the 3 hops.
__global__ __launch_bounds__(256) void k_spmm(const int* __restrict__ off,
                                              const int* __restrict__ sc,
                                              const float* __restrict__ sv,
                                              const float* __restrict__ hin,
                                              float* __restrict__ hout,
                                              float* __restrict__ acc,
                                              int n, int first) {
  int wid = (blockIdx.x * blockDim.x + threadIdx.x) >> 6;
  int lane = threadIdx.x & 63;
  if (wid >= n) return;
  int s = off[wid], e = off[wid + 1];
  float a = 0.f;
  for (int base = s; base < e; base += 64) {
    int c = 0;
    float v = 0.f;
    int idx = base + lane;
    if (idx < e) { c = sc[idx]; v = sv[idx]; }
    int m = min(64, e - base);
    #pragma unroll 4
    for (int j = 0; j < m; ++j) {
      int cj = __shfl(c, j, 64);
      float vj = __shfl(v, j, 64);
      a += vj * hin[(size_t)cj * 64 + lane];
    }
  }
  hout[(size_t)wid * 64 + lane] = a;
  float* ap = acc + (size_t)wid * 65 + 1 + lane;
  if (first) *ap = a;
  else *ap += a;
}

// acc (in d_out cols 1..64) -> out = [sqrt(max(1+||tail||^2, 1e-7)), tail],
// tail = sinh(nrm)/nrm * acc, nrm = max(||acc||, 1e-15)
__global__ __launch_bounds__(256) void k_final(float* __restrict__ out, int n) {
  int wid = (blockIdx.x * blockDim.x + threadIdx.x) >> 6;
  int lane = threadIdx.x & 63;
  if (wid >= n) return;
  float* row = out + (size_t)wid * 65;
  float a = row[1 + lane];
  float ss = waveReduceSum(a * a);
  float nrm = fmaxf(sqrtf(ss), 1e-15f);
  float sh = sinhf(nrm) / nrm;
  float tl = sh * a;
  float ss2 = waveReduceSum(tl * tl);
  float first = sqrtf(fmaxf(1.0f + ss2, 1e-7f));
  row[1 + lane] = tl;
  if (lane == 0) row[0] = first;
}

extern "C" void kernel_launch(void* const* d_in, const int* in_sizes, int n_in,
                              void* d_out, int out_size, void* d_ws, size_t ws_size,
                              hipStream_t stream) {
  const float* x = (const float*)d_in[0];
  const int* rows = (const int*)d_in[1];
  const int* cols = (const int*)d_in[2];
  const float* vals = (const float*)d_in[3];
  float* out = (float*)d_out;
  int n = in_sizes[0] / 65;
  int e = in_sizes[1];

  // workspace layout (~65 MB total)
  char* w = (char*)d_ws;
  auto alloc = [&](size_t bytes) {
    void* p = (void*)w;
    w += (bytes + 255) & ~(size_t)255;
    return p;
  };
  int* cnt  = (int*)alloc((size_t)n * 4);            // histogram -> cursor
  int* off  = (int*)alloc(((size_t)n + 1) * 4);      // CSR row offsets
  int* sc   = (int*)alloc((size_t)e * 4);            // bucketed cols
  float* sv = (float*)alloc((size_t)e * 4);          // bucketed vals
  float* h0 = (float*)alloc((size_t)n * 64 * 4);     // ping
  float* h1 = (float*)alloc((size_t)n * 64 * 4);     // pong

  hipMemsetAsync(cnt, 0, (size_t)n * 4, stream);

  int nwb = (n + 3) / 4;  // 4 waves (rows) per 256-thread block
  k_logmap0<<<nwb, 256, 0, stream>>>(x, h0, n);
  k_hist<<<2048, 256, 0, stream>>>(rows, cnt, e);
  k_scan<<<1, 1024, 0, stream>>>(cnt, off, n);
  k_scatter<<<2048, 256, 0, stream>>>(rows, cols, vals, cnt, sc, sv, e);

  k_spmm<<<nwb, 256, 0, stream>>>(off, sc, sv, h0, h1, out, n, 1);
  k_spmm<<<nwb, 256, 0, stream>>>(off, sc, sv, h1, h0, out, n, 0);
  k_spmm<<<nwb, 256, 0, stream>>>(off, sc, sv, h0, h1, out, n, 0);

  k_final<<<nwb, 256, 0, stream>>>(out, n);
}

// Round 4
// 631.061 us; speedup vs baseline: 1.3184x; 1.3184x over previous
//
#include <hip/hip_runtime.h>
#include <math.h>

// HyperbolicGraphConvolution on MI355X.
// N=100000 nodes, D=65 (col 0 identically 0 through GCN hops -> propagate 64),
// E=1.6M edges. CSR built per call (histogram + multi-block scan + scatter),
// then 3 gather SpMMs: one wave per row, lane d = feature d, edges broadcast
// via shfl, zero atomics in hot loop. 3-hop accumulator lives in d_out cols 1..64.

__device__ __forceinline__ float waveReduceSum(float v) {
  #pragma unroll
  for (int m = 32; m > 0; m >>= 1) v += __shfl_xor(v, m, 64);
  return v;
}

// t[i,d] = acosh(max(x[i,0], 1+1e-7)) * y_d / max(||y||, 1e-15), y = x[i,1:65]
__global__ __launch_bounds__(256) void k_logmap0(const float* __restrict__ x,
                                                 float* __restrict__ t, int n) {
  int wid = (blockIdx.x * blockDim.x + threadIdx.x) >> 6;
  int lane = threadIdx.x & 63;
  if (wid >= n) return;
  const float* row = x + (size_t)wid * 65;
  float x0 = row[0];
  float y = row[1 + lane];
  float ss = waveReduceSum(y * y);
  float nrm = fmaxf(sqrtf(ss), 1e-15f);
  float theta = fmaxf(x0, 1.0f + 1e-7f);
  t[(size_t)wid * 64 + lane] = acoshf(theta) * (y / nrm);
}

__global__ void k_hist(const int* __restrict__ rows, int* __restrict__ cnt, int e) {
  int i = blockIdx.x * blockDim.x + threadIdx.x;
  int stride = gridDim.x * blockDim.x;
  for (; i < e; i += stride) atomicAdd(&cnt[rows[i]], 1);
}

// ---- 3-phase multi-block exclusive scan over cnt[0..n) ----
// Phase 1: per-block (1024-wide) scan; exclusive-in-block -> off[i], total -> bsum[b]
__global__ __launch_bounds__(1024) void k_scan1(const int* __restrict__ cnt,
                                                int* __restrict__ off,
                                                int* __restrict__ bsum, int n) {
  __shared__ int sh[1024];
  int i = blockIdx.x * 1024 + threadIdx.x;
  int v = (i < n) ? cnt[i] : 0;
  sh[threadIdx.x] = v;
  __syncthreads();
  #pragma unroll
  for (int d = 1; d < 1024; d <<= 1) {
    int t = (threadIdx.x >= d) ? sh[threadIdx.x - d] : 0;
    __syncthreads();
    sh[threadIdx.x] += t;
    __syncthreads();
  }
  if (i < n) off[i] = sh[threadIdx.x] - v;
  if (threadIdx.x == 1023) bsum[blockIdx.x] = sh[1023];
}

// Phase 2: single block scans the (<=1024) block sums in-place -> exclusive
__global__ __launch_bounds__(1024) void k_scan2(int* __restrict__ bsum, int nb) {
  __shared__ int sh[1024];
  int v = (threadIdx.x < nb) ? bsum[threadIdx.x] : 0;
  sh[threadIdx.x] = v;
  __syncthreads();
  #pragma unroll
  for (int d = 1; d < 1024; d <<= 1) {
    int t = (threadIdx.x >= d) ? sh[threadIdx.x - d] : 0;
    __syncthreads();
    sh[threadIdx.x] += t;
    __syncthreads();
  }
  if (threadIdx.x < nb) bsum[threadIdx.x] = sh[threadIdx.x] - v;
}

// Phase 3: add block offset; off[i] final, cursor[i] = off[i]; off[n] = e
__global__ __launch_bounds__(1024) void k_scan3(int* __restrict__ off,
                                                const int* __restrict__ bsum,
                                                int* __restrict__ cursor,
                                                int n, int e) {
  int i = blockIdx.x * 1024 + threadIdx.x;
  if (i < n) {
    int o = off[i] + bsum[blockIdx.x];
    off[i] = o;
    cursor[i] = o;
  }
  if (i == 0) off[n] = e;
}

__global__ void k_scatter(const int* __restrict__ rows, const int* __restrict__ cols,
                          const float* __restrict__ vals, int* __restrict__ cursor,
                          int* __restrict__ sc, float* __restrict__ sv, int e) {
  int i = blockIdx.x * blockDim.x + threadIdx.x;
  int stride = gridDim.x * blockDim.x;
  for (; i < e; i += stride) {
    int r = rows[i];
    int p = atomicAdd(&cursor[r], 1);
    sc[p] = cols[i];
    sv[p] = vals[i];
  }
}

// One wave per row: lane d accumulates feature d over the row's edge bucket.
// Edge (col,val) pairs loaded coalesced 64-at-a-time, broadcast via shfl.
// acc points into d_out (stride 65, cols 1..64) and accumulates the 3 hops.
__global__ __launch_bounds__(256) void k_spmm(const int* __restrict__ off,
                                              const int* __restrict__ sc,
                                              const float* __restrict__ sv,
                                              const float* __restrict__ hin,
                                              float* __restrict__ hout,
                                              float* __restrict__ acc,
                                              int n, int first) {
  int wid = (blockIdx.x * blockDim.x + threadIdx.x) >> 6;
  int lane = threadIdx.x & 63;
  if (wid >= n) return;
  int s = off[wid], e = off[wid + 1];
  float a = 0.f;
  for (int base = s; base < e; base += 64) {
    int c = 0;
    float v = 0.f;
    int idx = base + lane;
    if (idx < e) { c = sc[idx]; v = sv[idx]; }
    int m = min(64, e - base);
    #pragma unroll 4
    for (int j = 0; j < m; ++j) {
      int cj = __shfl(c, j, 64);
      float vj = __shfl(v, j, 64);
      a += vj * hin[(size_t)cj * 64 + lane];
    }
  }
  hout[(size_t)wid * 64 + lane] = a;
  float* ap = acc + (size_t)wid * 65 + 1 + lane;
  if (first) *ap = a;
  else *ap += a;
}

// acc (in d_out cols 1..64) -> out = [sqrt(max(1+||tail||^2, 1e-7)), tail],
// tail = sinh(nrm)/nrm * acc, nrm = max(||acc||, 1e-15)
__global__ __launch_bounds__(256) void k_final(float* __restrict__ out, int n) {
  int wid = (blockIdx.x * blockDim.x + threadIdx.x) >> 6;
  int lane = threadIdx.x & 63;
  if (wid >= n) return;
  float* row = out + (size_t)wid * 65;
  float a = row[1 + lane];
  float ss = waveReduceSum(a * a);
  float nrm = fmaxf(sqrtf(ss), 1e-15f);
  float sh = sinhf(nrm) / nrm;
  float tl = sh * a;
  float ss2 = waveReduceSum(tl * tl);
  float first = sqrtf(fmaxf(1.0f + ss2, 1e-7f));
  row[1 + lane] = tl;
  if (lane == 0) row[0] = first;
}

extern "C" void kernel_launch(void* const* d_in, const int* in_sizes, int n_in,
                              void* d_out, int out_size, void* d_ws, size_t ws_size,
                              hipStream_t stream) {
  const float* x = (const float*)d_in[0];
  const int* rows = (const int*)d_in[1];
  const int* cols = (const int*)d_in[2];
  const float* vals = (const float*)d_in[3];
  float* out = (float*)d_out;
  int n = in_sizes[0] / 65;
  int e = in_sizes[1];

  // workspace layout (~65 MB total)
  char* w = (char*)d_ws;
  auto alloc = [&](size_t bytes) {
    void* p = (void*)w;
    w += (bytes + 255) & ~(size_t)255;
    return p;
  };
  int* cnt  = (int*)alloc((size_t)n * 4);            // histogram -> cursor
  int* off  = (int*)alloc(((size_t)n + 1) * 4);      // CSR row offsets
  int* bsum = (int*)alloc(1024 * 4);                 // scan block sums
  int* sc   = (int*)alloc((size_t)e * 4);            // bucketed cols
  float* sv = (float*)alloc((size_t)e * 4);          // bucketed vals
  float* h0 = (float*)alloc((size_t)n * 64 * 4);     // ping
  float* h1 = (float*)alloc((size_t)n * 64 * 4);     // pong

  hipMemsetAsync(cnt, 0, (size_t)n * 4, stream);

  int nwb = (n + 3) / 4;           // 4 waves (rows) per 256-thread block
  int nsb = (n + 1023) / 1024;     // scan blocks (98 for n=100000)

  k_logmap0<<<nwb, 256, 0, stream>>>(x, h0, n);
  k_hist<<<2048, 256, 0, stream>>>(rows, cnt, e);
  k_scan1<<<nsb, 1024, 0, stream>>>(cnt, off, bsum, n);
  k_scan2<<<1, 1024, 0, stream>>>(bsum, nsb);
  k_scan3<<<nsb, 1024, 0, stream>>>(off, bsum, cnt, n, e);
  k_scatter<<<2048, 256, 0, stream>>>(rows, cols, vals, cnt, sc, sv, e);

  k_spmm<<<nwb, 256, 0, stream>>>(off, sc, sv, h0, h1, out, n, 1);
  k_spmm<<<nwb, 256, 0, stream>>>(off, sc, sv, h1, h0, out, n, 0);
  k_spmm<<<nwb, 256, 0, stream>>>(off, sc, sv, h0, h1, out, n, 0);

  k_final<<<nwb, 256, 0, stream>>>(out, n);
}